// Round 10
// baseline (620.466 us; speedup 1.0000x reference)
//
#include <hip/hip_runtime.h>

// ---------- types ----------
// NOTE: gfx builtins (cvt_pkrtz, fdot2) use __fp16 ext-vectors, NOT _Float16.
typedef __fp16 f16x2 __attribute__((ext_vector_type(2)));

// ---------- lane/scalar helpers ----------
static __device__ __forceinline__ float rdlane(float v, int l) {
  return __uint_as_float(__builtin_amdgcn_readlane(__float_as_uint(v), (unsigned)l));
}
static __device__ __forceinline__ unsigned rdlane_u(unsigned v, int l) {
  return __builtin_amdgcn_readlane(v, (unsigned)l);
}

template <int CTRL>
static __device__ __forceinline__ float qperm(float v) {
  // DPP quad_perm: pure VALU cross-lane within each 4-lane quad.
  return __uint_as_float(__builtin_amdgcn_update_dpp(
      0u, __float_as_uint(v), CTRL, 0xF, 0xF, true));
}

// all lanes get (lo32-half value + hi32-half value) — verified R3-R9.
static __device__ __forceinline__ float xswapadd32(float v) {
  float a = v, b;
  asm("v_mov_b32 %0, %1\n\t"
      "s_nop 1\n\t"
      "v_permlane32_swap_b32 %1, %0"
      : "=&v"(b), "+v"(a));
  return a + b;
}

static __device__ __forceinline__ float exp2a(float x) {
  float r;
  asm("v_exp_f32 %0, %1" : "=v"(r) : "v"(x));
  return r;
}
static __device__ __forceinline__ float rcpa(float x) {
  return __builtin_amdgcn_rcpf(x);
}

// f32 += f16x2 . f16x2  (v_dot2_f32_f16: f16 multiply, f32 accumulate)
static __device__ __forceinline__ float dot2f(f16x2 a, unsigned bu, float c) {
#if __has_builtin(__builtin_amdgcn_fdot2)
  return __builtin_amdgcn_fdot2(a, __builtin_bit_cast(f16x2, bu), c, false);
#else
  float r = c;
  f16x2 b = __builtin_bit_cast(f16x2, bu);
  asm("v_dot2_f32_f16 %0, %1, %2, %0" : "+v"(r) : "v"(a), "v"(b));
  return r;
#endif
}

#define QP_XOR1 0xB1  // [1,0,3,2] — f to base
#define QP_XOR2 0x4E  // [2,3,0,1] — g to base
#define QP_XOR3 0x1B  // [3,2,1,0] — o to base
#define QP_BC0  0x00  // broadcast quad lane 0 (i)
#define QP_BC1  0x55  // broadcast quad lane 1 (f)
#define QP_BC2  0xAA  // broadcast quad lane 2 (g)
#define QP_BC3  0xFF  // broadcast quad lane 3 (o)

// lane = 4*j + gt (j: hidden unit 0..15, gt: gate i,f,g,o; torch row gt*16+j).
//
// Scale folding (R3): sigmoid rows *= -log2e, g rows *= -2log2e; g-gate
// output pre-scaled so cs = -2log2e*c; tanh(c) = 2*rcp(1+exp2(cs)) - 1.
// Pipeline (R4): body step g computes L2(g) and L1(g+1), both off h1(g).
// dot2 matvecs (R8): both layers share one f16 pair-broadcast, 8 SGPR pairs.
// VALU pair-build (R9): partner = xswapadd32(h) - h == h[lane^32].
//
// NEW (R10): trans count 8 -> 6 per step. L1 gates gathered to BASE lanes
// via 3 XOR qperms (h/cs only need validity on quad-base lanes — pair-build
// reads lanes 4m and 4m+32 only, all bases). Non-base lanes of cs are then
// free slots: cs2 (wave-uniform) is packed into lane 1 via one cndmask and
// ONE shared exp2/rcp computes tanh for BOTH cell states; tanh(cs2) comes
// back via readlane(.,1) -> SGPR multiply.
__global__ __launch_bounds__(64, 1) void vdd_lstm_kernel(
    const float* __restrict__ x,      // [B,T]
    const float* __restrict__ Wih1,   // [64]
    const float* __restrict__ Whh1,   // [64,16]
    const float* __restrict__ b1,     // [64]
    const float* __restrict__ Wih2,   // [4,16]
    const float* __restrict__ Whh2,   // [4]
    const float* __restrict__ b2,     // [4]
    const float* __restrict__ mask1,  // [B,16]
    const float* __restrict__ mask2,  // [B]
    float* __restrict__ out,          // [B,T]
    int T) {
  const int b = blockIdx.x;
  const int lane = threadIdx.x;  // 64 threads
  const int j = lane >> 2;
  const int gt = lane & 3;
  const int row = gt * 16 + j;

  const float LOG2E = 1.4426950408889634f;
  const bool isg = (gt == 2);
  const float sc = isg ? (-2.f * LOG2E) : (-LOG2E);
  const float aA = isg ? (-4.f * LOG2E) : 1.f;
  const float aC = isg ? (2.f * LOG2E) : 0.f;
  const bool isl1 = (lane == 1);  // loop-invariant lane mask (SGPR pair)

  // L1 weights as 8 f16 pairs {w[m], w[m+8]} (pre-scaled).
  f16x2 wh1[8];
#pragma unroll
  for (int m = 0; m < 8; ++m) {
    wh1[m].x = (__fp16)(Whh1[row * 16 + m] * sc);
    wh1[m].y = (__fp16)(Whh1[row * 16 + m + 8] * sc);
  }
  // L2 weights (mask1 + scale folded) as 8 f16 pairs {k=m, k=m+8}.
  f16x2 wh2[8];
#pragma unroll
  for (int m = 0; m < 8; ++m) {
    wh2[m].x = (__fp16)(Wih2[gt * 16 + m] * mask1[b * 16 + m] * sc);
    wh2[m].y = (__fp16)(Wih2[gt * 16 + m + 8] * mask1[b * 16 + m + 8] * sc);
  }
  const float wih1 = Wih1[row] * sc;
  const float bb1  = b1[row] * sc;
  const float whh2 = Whh2[gt] * sc;
  const float bb2  = b2[gt] * sc;
  const float m2   = mask2[b];

  const float* xb = x + (size_t)b * T;
  float* ob = out + (size_t)b * T;

  float h = 0.f, cs = 0.f;     // layer-1 state (valid on quad-BASE lanes)
  float cs2 = 0.f, h2b = 0.f;  // layer-2 state (all lanes)

  const int NCH = T >> 6;
  const int tmax = T - 1;

  // x window for chunk 0: x[1 + lane], clamped (coalesced).
  int idx0 = 1 + lane; idx0 = idx0 > tmax ? tmax : idx0;
  float xr = xb[idx0];

  // ---- prologue: layer-1 for step 0 (h_prev = 0), base-lane form ----
  {
    float x0 = xb[0];  // uniform
    float pre = __fmaf_rn(wih1, x0, bb1);
    float a1 = __fmaf_rn(aA, rcpa(1.f + exp2a(pre)), aC);
    float g1 = qperm<QP_XOR2>(a1);
    float o1 = qperm<QP_XOR3>(a1);
    cs = a1 * g1;  // i (at base) * g;  f*0 omitted
    float th = __fmaf_rn(2.f, rcpa(1.f + exp2a(cs)), -1.f);
    h = o1 * th;   // valid at base lanes
  }

  for (int ch = 0; ch < NCH; ++ch) {
    // prefetch next chunk's shifted window (clamped; coalesced)
    int idxn = (ch + 1) * 64 + 1 + lane;
    idxn = idxn > tmax ? tmax : idxn;
    float xnext = xb[idxn];

    float och = 0.f;  // lane L accumulates out[ch*64 + L]

#pragma unroll 8
    for (int s = 0; s < 64; ++s) {
      // ---- f16 pair-broadcast of h = h1(g), pure VALU ----
      // (base lane 4m sums with base lane 4m+32 — no garbage contamination)
      float hsum = xswapadd32(h);
      float partner = hsum - h;          // == h[lane^32] at base lanes
      f16x2 tp = __builtin_bit_cast(
          f16x2, __builtin_amdgcn_cvt_pkrtz(h, partner));
      unsigned tpu = __builtin_bit_cast(unsigned, tp);
      unsigned sp[8];
#pragma unroll
      for (int m = 0; m < 8; ++m) sp[m] = rdlane_u(tpu, 4 * m);

      float sx = rdlane(xr, s);  // x(g+1) — window pre-shifted by 1

      // ---- layer-1 pre-activation (step g+1): 8 dot2, 2 chains
      float accA = __fmaf_rn(wih1, sx, bb1);
      float accB = dot2f(wh1[1], sp[1], 0.f);
      accA = dot2f(wh1[0], sp[0], accA);
      accB = dot2f(wh1[3], sp[3], accB);
      accA = dot2f(wh1[2], sp[2], accA);
      accB = dot2f(wh1[5], sp[5], accB);
      accA = dot2f(wh1[4], sp[4], accA);
      accB = dot2f(wh1[7], sp[7], accB);
      accA = dot2f(wh1[6], sp[6], accA);
      float pre = accA + accB;

      // ---- layer-2 pre-activation (step g): same pairs, L2 weights
      float accC = __fmaf_rn(whh2, h2b, bb2);
      float accD = dot2f(wh2[1], sp[1], 0.f);
      accC = dot2f(wh2[0], sp[0], accC);
      accD = dot2f(wh2[3], sp[3], accD);
      accC = dot2f(wh2[2], sp[2], accC);
      accD = dot2f(wh2[5], sp[5], accD);
      accC = dot2f(wh2[4], sp[4], accC);
      accD = dot2f(wh2[7], sp[7], accD);
      accC = dot2f(wh2[6], sp[6], accC);
      float pre2 = accC + accD;

      // ---- layer-1 gates (base-lane form): 3 XOR qperms
      float a1 = __fmaf_rn(aA, rcpa(1.f + exp2a(pre)), aC);
      float f1 = qperm<QP_XOR1>(a1);
      float g1 = qperm<QP_XOR2>(a1);
      float o1 = qperm<QP_XOR3>(a1);
      cs = __fmaf_rn(f1, cs, a1 * g1);   // valid at base lanes (a1=i there)

      // ---- layer-2 gates (all lanes)
      float a2 = __fmaf_rn(aA, rcpa(1.f + exp2a(pre2)), aC);
      float i2 = qperm<QP_BC0>(a2);
      float f2 = qperm<QP_BC1>(a2);
      float g2 = qperm<QP_BC2>(a2);
      float o2 = qperm<QP_BC3>(a2);
      cs2 = __fmaf_rn(f2, cs2, i2 * g2);

      // ---- MERGED tanh: one exp2/rcp pair for tanh(cs) AND tanh(cs2)
      float z = isl1 ? cs2 : cs;         // cs2 packed into lane 1 (free slot)
      float thv = __fmaf_rn(2.f, rcpa(1.f + exp2a(z)), -1.f);
      float th2 = rdlane(thv, 1);        // tanh(cs2), SGPR
      float hn = o1 * thv;               // h(g+1), valid at base lanes
      h2b = o2 * th2;                    // h2(g), all lanes (VGPR * SGPR)
      float ov = h2b * m2;

      och = (lane == s) ? ov : och;
      h = hn;
    }

    ob[(ch << 6) + lane] = och;  // coalesced store
    xr = xnext;
  }
}

extern "C" void kernel_launch(void* const* d_in, const int* in_sizes, int n_in,
                              void* d_out, int out_size, void* d_ws, size_t ws_size,
                              hipStream_t stream) {
  const float* x     = (const float*)d_in[0];
  const float* Wih1  = (const float*)d_in[1];
  const float* Whh1  = (const float*)d_in[2];
  const float* b1    = (const float*)d_in[3];
  const float* Wih2  = (const float*)d_in[4];
  const float* Whh2  = (const float*)d_in[5];
  const float* b2    = (const float*)d_in[6];
  const float* mask1 = (const float*)d_in[7];
  const float* mask2 = (const float*)d_in[8];
  float* out = (float*)d_out;

  const int B = in_sizes[8];      // mask2 has B elements
  const int T = in_sizes[0] / B;  // x is [B,T,1]

  vdd_lstm_kernel<<<dim3(B), dim3(64), 0, stream>>>(
      x, Wih1, Whh1, b1, Wih2, Whh2, b2, mask1, mask2, out, T);
}

// Round 11
// 576.467 us; speedup vs baseline: 1.0763x; 1.0763x over previous
//
#include <hip/hip_runtime.h>

// ---------- types ----------
// NOTE: gfx builtins (cvt_pkrtz, fdot2) use __fp16 ext-vectors, NOT _Float16.
typedef __fp16 f16x2 __attribute__((ext_vector_type(2)));

// ---------- lane/scalar helpers ----------
static __device__ __forceinline__ float rdlane(float v, int l) {
  return __uint_as_float(__builtin_amdgcn_readlane(__float_as_uint(v), (unsigned)l));
}
static __device__ __forceinline__ unsigned rdlane_u(unsigned v, int l) {
  return __builtin_amdgcn_readlane(v, (unsigned)l);
}

template <int CTRL>
static __device__ __forceinline__ float qperm(float v) {
  // DPP quad_perm: pure VALU cross-lane within each 4-lane quad.
  return __uint_as_float(__builtin_amdgcn_update_dpp(
      0u, __float_as_uint(v), CTRL, 0xF, 0xF, true));
}

// all lanes get (lo32-half value + hi32-half value) — verified R3-R10.
static __device__ __forceinline__ float xswapadd32(float v) {
  float a = v, b;
  asm("v_mov_b32 %0, %1\n\t"
      "s_nop 1\n\t"
      "v_permlane32_swap_b32 %1, %0"
      : "=&v"(b), "+v"(a));
  return a + b;
}

static __device__ __forceinline__ float exp2a(float x) {
  float r;
  asm("v_exp_f32 %0, %1" : "=v"(r) : "v"(x));
  return r;
}
static __device__ __forceinline__ float rcpa(float x) {
  return __builtin_amdgcn_rcpf(x);
}

// f32 += f16x2 . f16x2  (v_dot2_f32_f16: f16 multiply, f32 accumulate)
static __device__ __forceinline__ float dot2f(f16x2 a, unsigned bu, float c) {
#if __has_builtin(__builtin_amdgcn_fdot2)
  return __builtin_amdgcn_fdot2(a, __builtin_bit_cast(f16x2, bu), c, false);
#else
  float r = c;
  f16x2 b = __builtin_bit_cast(f16x2, bu);
  asm("v_dot2_f32_f16 %0, %1, %2, %0" : "+v"(r) : "v"(a), "v"(b));
  return r;
#endif
}

#define QP_XOR1 0xB1  // [1,0,3,2] — f to base
#define QP_XOR2 0x4E  // [2,3,0,1] — g to base
#define QP_XOR3 0x1B  // [3,2,1,0] — o to base
#define QP_BC0  0x00  // broadcast quad lane 0 (i)
#define QP_BC1  0x55  // broadcast quad lane 1 (f)
#define QP_BC2  0xAA  // broadcast quad lane 2 (g)
#define QP_BC3  0xFF  // broadcast quad lane 3 (o)

// lane = 4*j + gt (j: hidden unit 0..15, gt: gate i,f,g,o; torch row gt*16+j).
//
// Scale folding (R3): sigmoid rows *= -log2e, g rows *= -2log2e; g-gate
// output pre-scaled so cs = -2log2e*c; tanh(c) = 2*rcp(1+exp2(cs)) - 1.
// dot2 matvecs (R8) on a shared f16 pair-broadcast; VALU pair-build (R9).
//
// R11 schedule (6 trans/body, decoupled): body t computes
//   pair(h(t)) -> L1 dots pre(t+1), L2 dots d2(t)
//   P1 sigmoid -> L1 gates -> cs(t+1)
//   P3 MERGED tanh: base lanes tanh(cs(t+1)); lane 1 tanh(cs2(t-1))  [old!]
//     -> hn = h(t+1);  th2 -> h2b = h2(t-1)
//   pre2(t) = whh2*h2(t-1) + d2(t) -> P2 sigmoid -> gates -> cs2(t), o2(t)
//   ov(t-1) = h2(t-1)*m2 -> och slot (t-1)&63
// Loop phased so chunk ch runs bodies t=ch*64+1..ch*64+64 (slots 0..63 of
// chunk ch) with a t=0 prologue body; store at chunk bottom.
__global__ __launch_bounds__(64, 1) void vdd_lstm_kernel(
    const float* __restrict__ x,      // [B,T]
    const float* __restrict__ Wih1,   // [64]
    const float* __restrict__ Whh1,   // [64,16]
    const float* __restrict__ b1,     // [64]
    const float* __restrict__ Wih2,   // [4,16]
    const float* __restrict__ Whh2,   // [4]
    const float* __restrict__ b2,     // [4]
    const float* __restrict__ mask1,  // [B,16]
    const float* __restrict__ mask2,  // [B]
    float* __restrict__ out,          // [B,T]
    int T) {
  const int b = blockIdx.x;
  const int lane = threadIdx.x;  // 64 threads
  const int j = lane >> 2;
  const int gt = lane & 3;
  const int row = gt * 16 + j;

  const float LOG2E = 1.4426950408889634f;
  const bool isg = (gt == 2);
  const float sc = isg ? (-2.f * LOG2E) : (-LOG2E);
  const float aA = isg ? (-4.f * LOG2E) : 1.f;
  const float aC = isg ? (2.f * LOG2E) : 0.f;
  const bool isl1 = (lane == 1);  // loop-invariant lane mask

  // L1 weights as 8 f16 pairs {w[m], w[m+8]} (pre-scaled).
  f16x2 wh1[8];
#pragma unroll
  for (int m = 0; m < 8; ++m) {
    wh1[m].x = (__fp16)(Whh1[row * 16 + m] * sc);
    wh1[m].y = (__fp16)(Whh1[row * 16 + m + 8] * sc);
  }
  // L2 weights (mask1 + scale folded) as 8 f16 pairs {k=m, k=m+8}.
  f16x2 wh2[8];
#pragma unroll
  for (int m = 0; m < 8; ++m) {
    wh2[m].x = (__fp16)(Wih2[gt * 16 + m] * mask1[b * 16 + m] * sc);
    wh2[m].y = (__fp16)(Wih2[gt * 16 + m + 8] * mask1[b * 16 + m + 8] * sc);
  }
  const float wih1 = Wih1[row] * sc;
  const float bb1  = b1[row] * sc;
  const float whh2 = Whh2[gt] * sc;
  const float bb2  = b2[gt] * sc;
  const float m2   = mask2[b];

  const float* xb = x + (size_t)b * T;
  float* ob = out + (size_t)b * T;

  float h, cs;                  // L1 state (valid on quad-BASE lanes)
  float cs2p = 0.f;             // cs2(t-1)
  float o2p = 0.f;              // o2(t-1)
  float och = 0.f;              // output chunk register

  const int NCH = T >> 6;
  const int tmax = T - 1;

  // ---- L1 step 0 (h_prev = 0), base-lane form ----
  {
    float pre = __fmaf_rn(wih1, xb[0], bb1);
    float a1 = __fmaf_rn(aA, rcpa(1.f + exp2a(pre)), aC);
    float g1 = qperm<QP_XOR2>(a1);
    float o1 = qperm<QP_XOR3>(a1);
    cs = a1 * g1;  // i (at base) * g
    float th = __fmaf_rn(2.f, rcpa(1.f + exp2a(cs)), -1.f);
    h = o1 * th;   // h1(0), valid at base lanes
  }

  // Body macro-equivalent (lambda): runs one pipeline body for step t.
  // sx = x(t+1). If doSel, selects ov(t-1) into och slot `slot`.
  auto body = [&](float sx, bool doSel, int slot) {
    // pair-build of h(t), pure VALU (base lanes pair with base lanes)
    float hsum = xswapadd32(h);
    float partner = hsum - h;          // == h[lane^32] at base lanes
    f16x2 tp = __builtin_bit_cast(
        f16x2, __builtin_amdgcn_cvt_pkrtz(h, partner));
    unsigned tpu = __builtin_bit_cast(unsigned, tp);
    unsigned sp[8];
#pragma unroll
    for (int m = 0; m < 8; ++m) sp[m] = rdlane_u(tpu, 4 * m);

    // L1 dots -> pre(t+1)
    float accA = __fmaf_rn(wih1, sx, bb1);
    float accB = dot2f(wh1[1], sp[1], 0.f);
    accA = dot2f(wh1[0], sp[0], accA);
    accB = dot2f(wh1[3], sp[3], accB);
    accA = dot2f(wh1[2], sp[2], accA);
    accB = dot2f(wh1[5], sp[5], accB);
    accA = dot2f(wh1[4], sp[4], accA);
    accB = dot2f(wh1[7], sp[7], accB);
    accA = dot2f(wh1[6], sp[6], accA);
    float pre = accA + accB;

    // L2 dots -> d2(t) = Wih2m . h(t) + bb2   (whh2 term joins later)
    float accC = dot2f(wh2[0], sp[0], bb2);
    float accD = dot2f(wh2[1], sp[1], 0.f);
    accC = dot2f(wh2[2], sp[2], accC);
    accD = dot2f(wh2[3], sp[3], accD);
    accC = dot2f(wh2[4], sp[4], accC);
    accD = dot2f(wh2[5], sp[5], accD);
    accC = dot2f(wh2[6], sp[6], accC);
    accD = dot2f(wh2[7], sp[7], accD);
    float d2 = accC + accD;

    // P1 sigmoid + L1 gates (base-lane form)
    float a1 = __fmaf_rn(aA, rcpa(1.f + exp2a(pre)), aC);
    float f1 = qperm<QP_XOR1>(a1);
    float g1 = qperm<QP_XOR2>(a1);
    float o1 = qperm<QP_XOR3>(a1);
    cs = __fmaf_rn(f1, cs, a1 * g1);   // cs(t+1), valid at base lanes

    // P3 merged tanh: base -> tanh(cs(t+1)); lane 1 -> tanh(cs2(t-1))
    float z = isl1 ? cs2p : cs;
    float thv = __fmaf_rn(2.f, rcpa(1.f + exp2a(z)), -1.f);
    float hn = o1 * thv;               // h(t+1) at base lanes
    float th2 = rdlane(thv, 1);        // tanh(cs2(t-1)), SGPR
    float h2b = o2p * th2;             // h2(t-1), uniform

    // pre2(t) -> P2 sigmoid -> L2 gates -> cs2(t), o2(t)
    float pre2 = __fmaf_rn(whh2, h2b, d2);
    float a2 = __fmaf_rn(aA, rcpa(1.f + exp2a(pre2)), aC);
    float i2 = qperm<QP_BC0>(a2);
    float f2 = qperm<QP_BC1>(a2);
    float g2 = qperm<QP_BC2>(a2);
    float o2n = qperm<QP_BC3>(a2);
    cs2p = __fmaf_rn(f2, cs2p, i2 * g2);  // cs2(t)
    o2p = o2n;                            // o2(t)

    // output for step t-1
    float ov = h2b * m2;
    if (doSel) och = (lane == slot) ? ov : och;
    h = hn;
  };

  // x window for chunk 0: w[lane] = x[2 + lane] (clamped)
  int idx0 = 2 + lane;
  idx0 = idx0 > tmax ? tmax : idx0;
  float w = xb[idx0];

  // ---- prologue body t=0 (produces ov(-1) = 0; no select) ----
  body(xb[1], false, 0);

  for (int ch = 0; ch < NCH; ++ch) {
    // prefetch next chunk's window: x[(ch+1)*64 + 2 + lane] (clamped)
    int idxn = (ch + 1) * 64 + 2 + lane;
    idxn = idxn > tmax ? tmax : idxn;
    float wn = xb[idxn];

#pragma unroll 8
    for (int s2 = 0; s2 < 64; ++s2) {
      // body t = ch*64 + 1 + s2; needs x(t+1) = x[ch*64 + 2 + s2] = w[s2]
      float sx = rdlane(w, s2);
      body(sx, true, s2);  // selects ov(t-1) into slot (t-1)&63 = s2
    }

    ob[(ch << 6) + lane] = och;  // chunk ch fully resident -> coalesced store
    w = wn;
  }
}

extern "C" void kernel_launch(void* const* d_in, const int* in_sizes, int n_in,
                              void* d_out, int out_size, void* d_ws, size_t ws_size,
                              hipStream_t stream) {
  const float* x     = (const float*)d_in[0];
  const float* Wih1  = (const float*)d_in[1];
  const float* Whh1  = (const float*)d_in[2];
  const float* b1    = (const float*)d_in[3];
  const float* Wih2  = (const float*)d_in[4];
  const float* Whh2  = (const float*)d_in[5];
  const float* b2    = (const float*)d_in[6];
  const float* mask1 = (const float*)d_in[7];
  const float* mask2 = (const float*)d_in[8];
  float* out = (float*)d_out;

  const int B = in_sizes[8];      // mask2 has B elements
  const int T = in_sizes[0] / B;  // x is [B,T,1]

  vdd_lstm_kernel<<<dim3(B), dim3(64), 0, stream>>>(
      x, Wih1, Whh1, b1, Wih2, Whh2, b2, mask1, mask2, out, T);
}

// Round 12
// 547.986 us; speedup vs baseline: 1.1323x; 1.0520x over previous
//
#include <hip/hip_runtime.h>

// ---------- types ----------
// NOTE: gfx builtins (cvt_pkrtz, fdot2) use __fp16 ext-vectors, NOT _Float16.
typedef __fp16 f16x2 __attribute__((ext_vector_type(2)));

// ---------- lane/scalar helpers ----------
static __device__ __forceinline__ float rdlane(float v, int l) {
  return __uint_as_float(__builtin_amdgcn_readlane(__float_as_uint(v), (unsigned)l));
}
static __device__ __forceinline__ unsigned rdlane_u(unsigned v, int l) {
  return __builtin_amdgcn_readlane(v, (unsigned)l);
}

template <int CTRL>
static __device__ __forceinline__ float qperm(float v) {
  // DPP quad_perm: pure VALU cross-lane within each 4-lane quad.
  return __uint_as_float(__builtin_amdgcn_update_dpp(
      0u, __float_as_uint(v), CTRL, 0xF, 0xF, true));
}

// v_permlane32_swap with a=b=v (distinct physical regs via explicit mov):
// vdst_upper <-> vsrc_lower  =>  a = {v_lo,v_lo}, b = {v_hi,v_hi}.
// At lanes<32: b[l] == v[l+32] — the cross-half partner, DIRECTLY.
// (Semantics validated via the permlane16 analog whose row-sum behavior
// R3's reduction depended on and ref-checked.) s_nop covers the
// VALU-write -> permlane-read wait-state hazard inside the asm.
static __device__ __forceinline__ float xswap_hi(float v) {
  float a = v, b;
  asm("v_mov_b32 %0, %1\n\t"
      "s_nop 1\n\t"
      "v_permlane32_swap_b32 %1, %0"
      : "=&v"(b), "+v"(a));
  return b;  // lanes<32: v[lane+32]
}

static __device__ __forceinline__ float exp2a(float x) {
  float r;
  asm("v_exp_f32 %0, %1" : "=v"(r) : "v"(x));
  return r;
}
static __device__ __forceinline__ float rcpa(float x) {
  return __builtin_amdgcn_rcpf(x);
}

// f32 += f16x2 . f16x2  (v_dot2_f32_f16: f16 multiply, f32 accumulate)
static __device__ __forceinline__ float dot2f(f16x2 a, unsigned bu, float c) {
#if __has_builtin(__builtin_amdgcn_fdot2)
  return __builtin_amdgcn_fdot2(a, __builtin_bit_cast(f16x2, bu), c, false);
#else
  float r = c;
  f16x2 b = __builtin_bit_cast(f16x2, bu);
  asm("v_dot2_f32_f16 %0, %1, %2, %0" : "+v"(r) : "v"(a), "v"(b));
  return r;
#endif
}

#define QP_XOR1 0xB1  // [1,0,3,2]
#define QP_XOR2 0x4E  // [2,3,0,1]
#define QP_XOR3 0x1B  // [3,2,1,0]
#define QP_BC0  0x00  // broadcast quad lane 0 (i)
#define QP_BC3  0xFF  // broadcast quad lane 3 (o)

// lane = 4*j + gt (j: hidden unit 0..15, gt: gate i,f,g,o; torch row gt*16+j).
//
// Scale folding (R3): sigmoid rows *= -log2e, g rows *= -2log2e; g-gate
// output pre-scaled so cs = -2log2e*c; tanh(c) = 2*rcp(1+exp2(cs)) - 1.
// dot2 matvecs (R8) on a shared f16 pair-broadcast; VALU pair-build (R9).
// R11 schedule (6 trans/body, decoupled merged tanh, one-body-lagged L2).
//
// R12: (1) partner via direct permlane32_swap output (drops add+sub);
//      (2) cs2 update valid at lane 1 only: at lane 1 a2==f,
//          qperm<XOR1>(a2)==i, qperm<XOR3>(a2)==g -> 2 qperms instead of
//          3 broadcasts (o2 keeps its BC3 broadcast for all lanes).
__global__ __launch_bounds__(64, 1) void vdd_lstm_kernel(
    const float* __restrict__ x,      // [B,T]
    const float* __restrict__ Wih1,   // [64]
    const float* __restrict__ Whh1,   // [64,16]
    const float* __restrict__ b1,     // [64]
    const float* __restrict__ Wih2,   // [4,16]
    const float* __restrict__ Whh2,   // [4]
    const float* __restrict__ b2,     // [4]
    const float* __restrict__ mask1,  // [B,16]
    const float* __restrict__ mask2,  // [B]
    float* __restrict__ out,          // [B,T]
    int T) {
  const int b = blockIdx.x;
  const int lane = threadIdx.x;  // 64 threads
  const int j = lane >> 2;
  const int gt = lane & 3;
  const int row = gt * 16 + j;

  const float LOG2E = 1.4426950408889634f;
  const bool isg = (gt == 2);
  const float sc = isg ? (-2.f * LOG2E) : (-LOG2E);
  const float aA = isg ? (-4.f * LOG2E) : 1.f;
  const float aC = isg ? (2.f * LOG2E) : 0.f;
  const bool isl1 = (lane == 1);  // loop-invariant lane mask

  // L1 weights as 8 f16 pairs {w[m], w[m+8]} (pre-scaled).
  f16x2 wh1[8];
#pragma unroll
  for (int m = 0; m < 8; ++m) {
    wh1[m].x = (__fp16)(Whh1[row * 16 + m] * sc);
    wh1[m].y = (__fp16)(Whh1[row * 16 + m + 8] * sc);
  }
  // L2 weights (mask1 + scale folded) as 8 f16 pairs {k=m, k=m+8}.
  f16x2 wh2[8];
#pragma unroll
  for (int m = 0; m < 8; ++m) {
    wh2[m].x = (__fp16)(Wih2[gt * 16 + m] * mask1[b * 16 + m] * sc);
    wh2[m].y = (__fp16)(Wih2[gt * 16 + m + 8] * mask1[b * 16 + m + 8] * sc);
  }
  const float wih1 = Wih1[row] * sc;
  const float bb1  = b1[row] * sc;
  const float whh2 = Whh2[gt] * sc;
  const float bb2  = b2[gt] * sc;
  const float m2   = mask2[b];

  const float* xb = x + (size_t)b * T;
  float* ob = out + (size_t)b * T;

  float h, cs;                  // L1 state (valid on quad-BASE lanes)
  float cs2p = 0.f;             // cs2(t-1)  (valid at lane 1)
  float o2p = 0.f;              // o2(t-1)   (all lanes)
  float och = 0.f;              // output chunk register

  const int NCH = T >> 6;
  const int tmax = T - 1;

  // ---- L1 step 0 (h_prev = 0), base-lane form ----
  {
    float pre = __fmaf_rn(wih1, xb[0], bb1);
    float a1 = __fmaf_rn(aA, rcpa(1.f + exp2a(pre)), aC);
    float g1 = qperm<QP_XOR2>(a1);
    float o1 = qperm<QP_XOR3>(a1);
    cs = a1 * g1;  // i (at base) * g
    float th = __fmaf_rn(2.f, rcpa(1.f + exp2a(cs)), -1.f);
    h = o1 * th;   // h1(0), valid at base lanes
  }

  // One pipeline body for step t. sx = x(t+1). If doSel, selects
  // ov(t-1) into och slot `slot`.
  auto body = [&](float sx, bool doSel, int slot) {
    // pair-build of h(t): partner comes straight out of the swap.
    float hhi = xswap_hi(h);           // lanes<32: h[lane+32]
    f16x2 tp = __builtin_bit_cast(
        f16x2, __builtin_amdgcn_cvt_pkrtz(h, hhi));
    unsigned tpu = __builtin_bit_cast(unsigned, tp);
    unsigned sp[8];
#pragma unroll
    for (int m = 0; m < 8; ++m) sp[m] = rdlane_u(tpu, 4 * m);  // lanes 0..28

    // L1 dots -> pre(t+1)
    float accA = __fmaf_rn(wih1, sx, bb1);
    float accB = dot2f(wh1[1], sp[1], 0.f);
    accA = dot2f(wh1[0], sp[0], accA);
    accB = dot2f(wh1[3], sp[3], accB);
    accA = dot2f(wh1[2], sp[2], accA);
    accB = dot2f(wh1[5], sp[5], accB);
    accA = dot2f(wh1[4], sp[4], accA);
    accB = dot2f(wh1[7], sp[7], accB);
    accA = dot2f(wh1[6], sp[6], accA);
    float pre = accA + accB;

    // L2 dots -> d2(t) = Wih2m . h(t) + bb2
    float accC = dot2f(wh2[0], sp[0], bb2);
    float accD = dot2f(wh2[1], sp[1], 0.f);
    accC = dot2f(wh2[2], sp[2], accC);
    accD = dot2f(wh2[3], sp[3], accD);
    accC = dot2f(wh2[4], sp[4], accC);
    accD = dot2f(wh2[5], sp[5], accD);
    accC = dot2f(wh2[6], sp[6], accC);
    accD = dot2f(wh2[7], sp[7], accD);
    float d2 = accC + accD;

    // P1 sigmoid + L1 gates (base-lane form)
    float a1 = __fmaf_rn(aA, rcpa(1.f + exp2a(pre)), aC);
    float f1 = qperm<QP_XOR1>(a1);
    float g1 = qperm<QP_XOR2>(a1);
    float o1 = qperm<QP_XOR3>(a1);
    cs = __fmaf_rn(f1, cs, a1 * g1);   // cs(t+1), valid at base lanes

    // P3 merged tanh: base -> tanh(cs(t+1)); lane 1 -> tanh(cs2(t-1))
    float z = isl1 ? cs2p : cs;
    float thv = __fmaf_rn(2.f, rcpa(1.f + exp2a(z)), -1.f);
    float hn = o1 * thv;               // h(t+1) at base lanes
    float th2 = rdlane(thv, 1);        // tanh(cs2(t-1)), SGPR
    float h2b = o2p * th2;             // h2(t-1), uniform

    // pre2(t) -> P2 sigmoid -> L2 gates
    float pre2 = __fmaf_rn(whh2, h2b, d2);
    float a2 = __fmaf_rn(aA, rcpa(1.f + exp2a(pre2)), aC);
    // cs2 update, lane-1-only: a2@1=f, qXOR1@1=i, qXOR3@1=g
    float i2l = qperm<QP_XOR1>(a2);
    float g2l = qperm<QP_XOR3>(a2);
    cs2p = __fmaf_rn(a2, cs2p, i2l * g2l);  // cs2(t) at lane 1
    o2p = qperm<QP_BC3>(a2);                // o2(t), all lanes

    // output for step t-1
    float ov = h2b * m2;
    if (doSel) och = (lane == slot) ? ov : och;
    h = hn;
  };

  // x window for chunk 0: w[lane] = x[2 + lane] (clamped)
  int idx0 = 2 + lane;
  idx0 = idx0 > tmax ? tmax : idx0;
  float w = xb[idx0];

  // ---- prologue body t=0 (produces ov(-1) = 0; no select) ----
  body(xb[1], false, 0);

  for (int ch = 0; ch < NCH; ++ch) {
    // prefetch next chunk's window: x[(ch+1)*64 + 2 + lane] (clamped)
    int idxn = (ch + 1) * 64 + 2 + lane;
    idxn = idxn > tmax ? tmax : idxn;
    float wn = xb[idxn];

#pragma unroll 8
    for (int s2 = 0; s2 < 64; ++s2) {
      // body t = ch*64 + 1 + s2; needs x(t+1) = x[ch*64 + 2 + s2] = w[s2]
      float sx = rdlane(w, s2);
      body(sx, true, s2);  // selects ov(t-1) into slot (t-1)&63 = s2
    }

    ob[(ch << 6) + lane] = och;  // chunk ch fully resident -> coalesced store
    w = wn;
  }
}

extern "C" void kernel_launch(void* const* d_in, const int* in_sizes, int n_in,
                              void* d_out, int out_size, void* d_ws, size_t ws_size,
                              hipStream_t stream) {
  const float* x     = (const float*)d_in[0];
  const float* Wih1  = (const float*)d_in[1];
  const float* Whh1  = (const float*)d_in[2];
  const float* b1    = (const float*)d_in[3];
  const float* Wih2  = (const float*)d_in[4];
  const float* Whh2  = (const float*)d_in[5];
  const float* b2    = (const float*)d_in[6];
  const float* mask1 = (const float*)d_in[7];
  const float* mask2 = (const float*)d_in[8];
  float* out = (float*)d_out;

  const int B = in_sizes[8];      // mask2 has B elements
  const int T = in_sizes[0] / B;  // x is [B,T,1]

  vdd_lstm_kernel<<<dim3(B), dim3(64), 0, stream>>>(
      x, Wih1, Whh1, b1, Wih2, Whh2, b2, mask1, mask2, out, T);
}

// Round 13
// 538.989 us; speedup vs baseline: 1.1512x; 1.0167x over previous
//
#include <hip/hip_runtime.h>

// ---------- types ----------
// NOTE: gfx builtins (cvt_pkrtz, fdot2) use __fp16 ext-vectors, NOT _Float16.
typedef __fp16 f16x2 __attribute__((ext_vector_type(2)));
typedef unsigned u32x2 __attribute__((ext_vector_type(2)));

// ---------- lane/scalar helpers ----------
static __device__ __forceinline__ float rdlane(float v, int l) {
  return __uint_as_float(__builtin_amdgcn_readlane(__float_as_uint(v), (unsigned)l));
}
static __device__ __forceinline__ unsigned rdlane_u(unsigned v, int l) {
  return __builtin_amdgcn_readlane(v, (unsigned)l);
}

template <int CTRL>
static __device__ __forceinline__ float qperm(float v) {
  // DPP quad_perm: pure VALU cross-lane within each 4-lane quad.
  return __uint_as_float(__builtin_amdgcn_update_dpp(
      0u, __float_as_uint(v), CTRL, 0xF, 0xF, true));
}

// v_permlane32_swap with vdst=vsrc=v. Hardware-validated mapping (R12
// refcheck): the VSRC result has, at lanes<32, v[lane+32] (vdst's upper
// half moved into vsrc's lower half). Builtin form lets the compiler
// schedule around it and insert exact hazard nops (vs the old asm block
// with a fixed s_nop + scheduling barrier on the h-chain).
static __device__ __forceinline__ float xswap_hi(float v) {
#if __has_builtin(__builtin_amdgcn_permlane32_swap)
  u32x2 r = __builtin_amdgcn_permlane32_swap(
      __float_as_uint(v), __float_as_uint(v), false, false);
  return __uint_as_float(r.y);  // vsrc result: lanes<32 hold v[lane+32]
#else
  float a = v, b;
  asm("v_mov_b32 %0, %1\n\t"
      "s_nop 1\n\t"
      "v_permlane32_swap_b32 %1, %0"
      : "=&v"(b), "+v"(a));
  return b;
#endif
}

static __device__ __forceinline__ float exp2a(float x) {
  float r;
  asm("v_exp_f32 %0, %1" : "=v"(r) : "v"(x));
  return r;
}
static __device__ __forceinline__ float rcpa(float x) {
  return __builtin_amdgcn_rcpf(x);
}

// f32 += f16x2 . f16x2  (v_dot2_f32_f16: f16 multiply, f32 accumulate)
static __device__ __forceinline__ float dot2f(f16x2 a, unsigned bu, float c) {
#if __has_builtin(__builtin_amdgcn_fdot2)
  return __builtin_amdgcn_fdot2(a, __builtin_bit_cast(f16x2, bu), c, false);
#else
  float r = c;
  f16x2 b = __builtin_bit_cast(f16x2, bu);
  asm("v_dot2_f32_f16 %0, %1, %2, %0" : "+v"(r) : "v"(a), "v"(b));
  return r;
#endif
}

#define QP_XOR1 0xB1  // [1,0,3,2]
#define QP_XOR2 0x4E  // [2,3,0,1]
#define QP_XOR3 0x1B  // [3,2,1,0]
#define QP_BC3  0xFF  // broadcast quad lane 3 (o)

// lane = 4*j + gt (j: hidden unit 0..15, gt: gate i,f,g,o; torch row gt*16+j).
//
// Scale folding (R3): sigmoid rows *= -log2e, g rows *= -2log2e; g-gate
// output pre-scaled so cs = -2log2e*c; tanh(c) = 2*rcp(1+exp2(cs)) - 1.
// dot2 matvecs (R8) on a shared f16 pair-broadcast; VALU pair-build (R9).
// R11 schedule (6 trans/body, decoupled merged tanh, one-body-lagged L2).
// R12: direct-partner swap; lane-1-only cs2 update.
// R13: builtin permlane swap (scheduler-friendly, no fixed s_nop);
//      unroll 16 for a wider cross-body scheduling window.
__global__ __launch_bounds__(64, 1) void vdd_lstm_kernel(
    const float* __restrict__ x,      // [B,T]
    const float* __restrict__ Wih1,   // [64]
    const float* __restrict__ Whh1,   // [64,16]
    const float* __restrict__ b1,     // [64]
    const float* __restrict__ Wih2,   // [4,16]
    const float* __restrict__ Whh2,   // [4]
    const float* __restrict__ b2,     // [4]
    const float* __restrict__ mask1,  // [B,16]
    const float* __restrict__ mask2,  // [B]
    float* __restrict__ out,          // [B,T]
    int T) {
  const int b = blockIdx.x;
  const int lane = threadIdx.x;  // 64 threads
  const int j = lane >> 2;
  const int gt = lane & 3;
  const int row = gt * 16 + j;

  const float LOG2E = 1.4426950408889634f;
  const bool isg = (gt == 2);
  const float sc = isg ? (-2.f * LOG2E) : (-LOG2E);
  const float aA = isg ? (-4.f * LOG2E) : 1.f;
  const float aC = isg ? (2.f * LOG2E) : 0.f;
  const bool isl1 = (lane == 1);  // loop-invariant lane mask

  // L1 weights as 8 f16 pairs {w[m], w[m+8]} (pre-scaled).
  f16x2 wh1[8];
#pragma unroll
  for (int m = 0; m < 8; ++m) {
    wh1[m].x = (__fp16)(Whh1[row * 16 + m] * sc);
    wh1[m].y = (__fp16)(Whh1[row * 16 + m + 8] * sc);
  }
  // L2 weights (mask1 + scale folded) as 8 f16 pairs {k=m, k=m+8}.
  f16x2 wh2[8];
#pragma unroll
  for (int m = 0; m < 8; ++m) {
    wh2[m].x = (__fp16)(Wih2[gt * 16 + m] * mask1[b * 16 + m] * sc);
    wh2[m].y = (__fp16)(Wih2[gt * 16 + m + 8] * mask1[b * 16 + m + 8] * sc);
  }
  const float wih1 = Wih1[row] * sc;
  const float bb1  = b1[row] * sc;
  const float whh2 = Whh2[gt] * sc;
  const float bb2  = b2[gt] * sc;
  const float m2   = mask2[b];

  const float* xb = x + (size_t)b * T;
  float* ob = out + (size_t)b * T;

  float h, cs;                  // L1 state (valid on quad-BASE lanes)
  float cs2p = 0.f;             // cs2(t-1)  (valid at lane 1)
  float o2p = 0.f;              // o2(t-1)   (all lanes)
  float och = 0.f;              // output chunk register

  const int NCH = T >> 6;
  const int tmax = T - 1;

  // ---- L1 step 0 (h_prev = 0), base-lane form ----
  {
    float pre = __fmaf_rn(wih1, xb[0], bb1);
    float a1 = __fmaf_rn(aA, rcpa(1.f + exp2a(pre)), aC);
    float g1 = qperm<QP_XOR2>(a1);
    float o1 = qperm<QP_XOR3>(a1);
    cs = a1 * g1;  // i (at base) * g
    float th = __fmaf_rn(2.f, rcpa(1.f + exp2a(cs)), -1.f);
    h = o1 * th;   // h1(0), valid at base lanes
  }

  // One pipeline body for step t. sx = x(t+1). If doSel, selects
  // ov(t-1) into och slot `slot`.
  auto body = [&](float sx, bool doSel, int slot) {
    // pair-build of h(t): partner straight out of the permlane swap.
    float hhi = xswap_hi(h);           // lanes<32: h[lane+32]
    f16x2 tp = __builtin_bit_cast(
        f16x2, __builtin_amdgcn_cvt_pkrtz(h, hhi));
    unsigned tpu = __builtin_bit_cast(unsigned, tp);
    unsigned sp[8];
#pragma unroll
    for (int m = 0; m < 8; ++m) sp[m] = rdlane_u(tpu, 4 * m);  // lanes 0..28

    // L1 dots -> pre(t+1)
    float accA = __fmaf_rn(wih1, sx, bb1);
    float accB = dot2f(wh1[1], sp[1], 0.f);
    accA = dot2f(wh1[0], sp[0], accA);
    accB = dot2f(wh1[3], sp[3], accB);
    accA = dot2f(wh1[2], sp[2], accA);
    accB = dot2f(wh1[5], sp[5], accB);
    accA = dot2f(wh1[4], sp[4], accA);
    accB = dot2f(wh1[7], sp[7], accB);
    accA = dot2f(wh1[6], sp[6], accA);
    float pre = accA + accB;

    // L2 dots -> d2(t) = Wih2m . h(t) + bb2
    float accC = dot2f(wh2[0], sp[0], bb2);
    float accD = dot2f(wh2[1], sp[1], 0.f);
    accC = dot2f(wh2[2], sp[2], accC);
    accD = dot2f(wh2[3], sp[3], accD);
    accC = dot2f(wh2[4], sp[4], accC);
    accD = dot2f(wh2[5], sp[5], accD);
    accC = dot2f(wh2[6], sp[6], accC);
    accD = dot2f(wh2[7], sp[7], accD);
    float d2 = accC + accD;

    // P1 sigmoid + L1 gates (base-lane form)
    float a1 = __fmaf_rn(aA, rcpa(1.f + exp2a(pre)), aC);
    float f1 = qperm<QP_XOR1>(a1);
    float g1 = qperm<QP_XOR2>(a1);
    float o1 = qperm<QP_XOR3>(a1);
    cs = __fmaf_rn(f1, cs, a1 * g1);   // cs(t+1), valid at base lanes

    // P3 merged tanh: base -> tanh(cs(t+1)); lane 1 -> tanh(cs2(t-1))
    float z = isl1 ? cs2p : cs;
    float thv = __fmaf_rn(2.f, rcpa(1.f + exp2a(z)), -1.f);
    float hn = o1 * thv;               // h(t+1) at base lanes
    float th2 = rdlane(thv, 1);        // tanh(cs2(t-1)), SGPR
    float h2b = o2p * th2;             // h2(t-1), uniform

    // pre2(t) -> P2 sigmoid -> L2 gates
    float pre2 = __fmaf_rn(whh2, h2b, d2);
    float a2 = __fmaf_rn(aA, rcpa(1.f + exp2a(pre2)), aC);
    // cs2 update, lane-1-only: a2@1=f, qXOR1@1=i, qXOR3@1=g
    float i2l = qperm<QP_XOR1>(a2);
    float g2l = qperm<QP_XOR3>(a2);
    cs2p = __fmaf_rn(a2, cs2p, i2l * g2l);  // cs2(t) at lane 1
    o2p = qperm<QP_BC3>(a2);                // o2(t), all lanes

    // output for step t-1
    float ov = h2b * m2;
    if (doSel) och = (lane == slot) ? ov : och;
    h = hn;
  };

  // x window for chunk 0: w[lane] = x[2 + lane] (clamped)
  int idx0 = 2 + lane;
  idx0 = idx0 > tmax ? tmax : idx0;
  float w = xb[idx0];

  // ---- prologue body t=0 (produces ov(-1) = 0; no select) ----
  body(xb[1], false, 0);

  for (int ch = 0; ch < NCH; ++ch) {
    // prefetch next chunk's window: x[(ch+1)*64 + 2 + lane] (clamped)
    int idxn = (ch + 1) * 64 + 2 + lane;
    idxn = idxn > tmax ? tmax : idxn;
    float wn = xb[idxn];

#pragma unroll 16
    for (int s2 = 0; s2 < 64; ++s2) {
      // body t = ch*64 + 1 + s2; needs x(t+1) = x[ch*64 + 2 + s2] = w[s2]
      float sx = rdlane(w, s2);
      body(sx, true, s2);  // selects ov(t-1) into slot (t-1)&63 = s2
    }

    ob[(ch << 6) + lane] = och;  // chunk ch fully resident -> coalesced store
    w = wn;
  }
}

extern "C" void kernel_launch(void* const* d_in, const int* in_sizes, int n_in,
                              void* d_out, int out_size, void* d_ws, size_t ws_size,
                              hipStream_t stream) {
  const float* x     = (const float*)d_in[0];
  const float* Wih1  = (const float*)d_in[1];
  const float* Whh1  = (const float*)d_in[2];
  const float* b1    = (const float*)d_in[3];
  const float* Wih2  = (const float*)d_in[4];
  const float* Whh2  = (const float*)d_in[5];
  const float* b2    = (const float*)d_in[6];
  const float* mask1 = (const float*)d_in[7];
  const float* mask2 = (const float*)d_in[8];
  float* out = (float*)d_out;

  const int B = in_sizes[8];      // mask2 has B elements
  const int T = in_sizes[0] / B;  // x is [B,T,1]

  vdd_lstm_kernel<<<dim3(B), dim3(64), 0, stream>>>(
      x, Wih1, Whh1, b1, Wih2, Whh2, b2, mask1, mask2, out, T);
}